// Round 6
// baseline (937.562 us; speedup 1.0000x reference)
//
#include <hip/hip_runtime.h>
#include <hip/hip_bf16.h>
#include <cstdint>

#define LH   50
#define PP   30
#define NAG  2048
#define NHID 128
#define EHID 256
#define ADIM 64
#define CNND 2048

typedef __attribute__((ext_vector_type(8))) short bf16x8;
typedef __attribute__((ext_vector_type(4))) float f32x4;

// ---- workspace layout (float slots) -----------------------------------------
enum : int {
  WS_WT  = 0,        // bf16 plain chunks c=0..3  [c][j=1024][k'=32]  -> 65536 fl (256KB)
  WS_WZ  = 65536,    // bf16 SWIZZLED image chunks c=4..7 [c][r=512][p=8][8] -> 65536 fl
  WS_WHT = 131072,   // bf16 WhtT[512][128]       -> 32768
  WS_WFN = 163840,   // 2*1024 folded (W_nemb@Wih_n)
  WS_BFN = 165888,   // 1024
  WS_WFT = 166912,   // 2*512 folded (W_temb@Wih_t)
  WS_BFT = 167936,   // 512
  WS_TH  = 168448,   // 128  (th after obs chain)
  WS_TC  = 168576,   // 128
  WS_W49 = 168704,   // 2048 obs softmax weights
  WS_CN  = 170752,   // 1    currN(49)
  WS_Z   = 170756,   // 30*2048*2 = 122880
  WS_END = 293636
};

#define HLROW 280   // shorts per Hl row (256 data + pad; 560B stride, ~2-way banks)

__device__ __forceinline__ float sigf(float x){ return 1.0f/(1.0f + __expf(-x)); }
__device__ __forceinline__ float tanhfast(float x){
  x = fminf(15.0f, fmaxf(-15.0f, x));
  float e = __expf(2.0f*x);
  return (e - 1.0f)/(e + 1.0f);
}
__device__ __forceinline__ float bfs(short s){
  return __uint_as_float(((unsigned)(unsigned short)s) << 16);
}
__device__ __forceinline__ void gld16(const void* g, void* l){
  __builtin_amdgcn_global_load_lds(
      (const __attribute__((address_space(1))) unsigned int*)g,
      (__attribute__((address_space(3))) unsigned int*)l, 16, 0, 0);
}

// ---- prep --------------------------------------------------------------------
// blocks 0..127  : plain chunks c=0..3 (k in [0,128)), layout [c][j][k'32]
// blocks 128..191: swizzled image for chunks c=4..7 (k in [128,256))
// block  192     : folds + WhtT
__global__ void k_prep(const float* __restrict__ Whhn, const float* __restrict__ Whht,
                       const float* __restrict__ Wnemb, const float* __restrict__ bnemb,
                       const float* __restrict__ Wihn,  const float* __restrict__ bihn,
                       const float* __restrict__ bhhn,
                       const float* __restrict__ Wtemb, const float* __restrict__ btemb,
                       const float* __restrict__ Wiht,  const float* __restrict__ biht,
                       const float* __restrict__ bhht,
                       float* __restrict__ ws)
{
  const int b = blockIdx.x, tid = threadIdx.x;
  if (b < 128){
    __shared__ float t[32][33];
    __hip_bfloat16* WT = (__hip_bfloat16*)(ws + WS_WT);
    const int tx = tid & 31, ty = tid >> 5;     // ty in [0,8)
    const int j0 = (b & 31) << 5;
    const int e0 = (b >> 5) << 5;               // e0 in [0,128)
    #pragma unroll
    for (int r = 0; r < 4; ++r)
      t[ty + 8*r][tx] = Whhn[(e0 + ty + 8*r)*1024 + j0 + tx];
    __syncthreads();
    const int c = e0 >> 5;                      // 0..3
    #pragma unroll
    for (int r = 0; r < 4; ++r)
      WT[c*32768 + (j0 + ty + 8*r)*32 + tx] = __float2bfloat16(t[tx][ty + 8*r]);
  } else if (b < 192){
    // swizzled image: element (c, r, p, i):
    //   ls = p ^ (r&7); j = (ls>>2)*512 + r; k = (4+c)*32 + (ls&3)*8 + i
    __hip_bfloat16* WZ = (__hip_bfloat16*)(ws + WS_WZ);
    const int bb = b - 128;
    const int c  = bb >> 4;            // 0..3  (logical chunk 4+c)
    const int r0 = (bb & 15) << 5;     // 32 rows per block
    const int r  = r0 + (tid >> 3);
    const int p  = tid & 7;
    const int ls = p ^ (r & 7);
    const int j  = ((ls >> 2) << 9) + r;
    const int kb = (4 + c)*32 + (ls & 3)*8;
    #pragma unroll
    for (int i = 0; i < 8; ++i)
      WZ[((c*512 + r)*8 + p)*8 + i] = __float2bfloat16(Whhn[(kb + i)*1024 + j]);
  } else {
    for (int j = tid; j < 1024; j += 256){
      float a0=0.f, a1=0.f, ab=0.f;
      for (int k=0;k<64;k++){
        const float w = Wihn[k*1024 + j];
        a0 += Wnemb[k]*w; a1 += Wnemb[64+k]*w; ab += bnemb[k]*w;
      }
      ws[WS_WFN + j]        = a0;
      ws[WS_WFN + 1024 + j] = a1;
      ws[WS_BFN + j]        = ab + bihn[j] + bhhn[j];
    }
    for (int j = tid; j < 512; j += 256){
      float a0=0.f, a1=0.f, ab=0.f;
      for (int k=0;k<64;k++){
        const float w = Wiht[k*512 + j];
        a0 += Wtemb[k]*w; a1 += Wtemb[64+k]*w; ab += btemb[k]*w;
      }
      ws[WS_WFT + j]       = a0;
      ws[WS_WFT + 512 + j] = a1;
      ws[WS_BFT + j]       = ab + biht[j] + bhht[j];
    }
    __hip_bfloat16* WTt = (__hip_bfloat16*)(ws + WS_WHT);
    for (int j = tid; j < 512; j += 256)
      for (int k = 0; k < 128; ++k)
        WTt[j*128 + k] = __float2bfloat16(Whht[k*512 + j]);
  }
}

// ---- Phase A ------------------------------------------------------------------
// blocks 0..127: nearby chain, 16 agents, 78 steps.
//   k in [0,128): B-frags register-resident (wreg, 128 VGPR).
//   k in [128,256): 4 chunks of 64KB streamed via global_load_lds, 2-buf,
//   counted vmcnt(8) (never drained in-loop), swizzled image.
// block 128: target obs chain.  block 129: w49 precompute.
// dynamic LDS: wbuf 2x65536B | Hl 16*HLROW shorts | relS 1600 f | vS 512 f
__global__ __launch_bounds__(512, 2) void k_phaseA(
    const float* __restrict__ nh0, const float* __restrict__ nc0,
    const float* __restrict__ nrel, const int* __restrict__ nhist,
    const float* __restrict__ Wpred,
    const float* __restrict__ trel, const int* __restrict__ thsp,
    const float* __restrict__ Whht, const float* __restrict__ th0,
    const float* __restrict__ tc0,
    const float* __restrict__ tpos, const float* __restrict__ npos,
    const float* __restrict__ Wtatt, const float* __restrict__ btatt,
    const float* __restrict__ Wnatt, const float* __restrict__ bnatt,
    float* __restrict__ ws)
{
  extern __shared__ char smem_raw[];
  const int b = blockIdx.x, tid = threadIdx.x;
  const int wv = tid >> 6, lane = tid & 63;
  const int lhi = lane >> 4, llo = lane & 15;

  if (b < 128){
    short* wbuf = (short*)smem_raw;                        // 2 x 32768 shorts
    short* Hl   = (short*)(smem_raw + 131072);             // 16 x HLROW shorts
    float* relS = (float*)(smem_raw + 131072 + 16*HLROW*2);
    float* vS   = relS + 1600;
    const int n0 = b << 4;

    // issue prologue stages: logical chunks 4,5 -> buf 0,1
    {
      const char* wz = (const char*)(ws + WS_WZ);
      #pragma unroll
      for (int bufc = 0; bufc < 2; ++bufc){
        const char* gsrc = wz + bufc*65536 + wv*8192 + lane*16;
        char* ldst = smem_raw + bufc*65536 + wv*8192;
        #pragma unroll
        for (int i = 0; i < 8; ++i) gld16(gsrc + i*1024, ldst + i*1024);
      }
    }
    // register-resident B-frags for k in [0,128)
    bf16x8 wreg[4][2][4];
    {
      const short* wt = (const short*)(ws + WS_WT);
      #pragma unroll
      for (int g = 0; g < 4; ++g)
        #pragma unroll
        for (int t = 0; t < 2; ++t){
          const int j = g*256 + (wv<<5) + t*16 + llo;
          #pragma unroll
          for (int ks = 0; ks < 4; ++ks)
            wreg[g][t][ks] = *(const bf16x8*)(wt + ks*32768 + j*32 + lhi*8);
        }
    }
    for (int i = tid; i < 1600; i += 512){
      const int a = i / 100, r = i % 100;
      relS[a*100 + r] = nrel[(n0 + a)*100 + r];
    }
    if (tid < 256){
      vS[2*tid]   = Wpred[2*(NHID + CNND + tid)];
      vS[2*tid+1] = Wpred[2*(NHID + CNND + tid) + 1];
    }
    for (int i = tid; i < 4096; i += 512){
      const int a = i >> 8, e = i & 255;
      ((__hip_bfloat16*)Hl)[a*HLROW + e] = __float2bfloat16(nh0[e]);
    }
    float wf0[4][2], wf1[4][2], wb[4][2];
    #pragma unroll
    for (int g = 0; g < 4; ++g)
      #pragma unroll
      for (int t = 0; t < 2; ++t){
        const int j = g*256 + (wv<<5) + t*16 + llo;
        wf0[g][t] = ws[WS_WFN + j];
        wf1[g][t] = ws[WS_WFN + 1024 + j];
        wb [g][t] = ws[WS_BFN + j];
      }
    float C[4][2], ho[4][2];
    #pragma unroll
    for (int r = 0; r < 4; ++r)
      #pragma unroll
      for (int t = 0; t < 2; ++t){
        const int eo = (wv<<5) + t*16 + llo;
        C[r][t]  = nc0[eo];
        ho[r][t] = nh0[eo];
      }
    int nh4[4];
    #pragma unroll
    for (int r = 0; r < 4; ++r) nh4[r] = nhist[n0 + lhi*4 + r];

    __syncthreads();   // one-time full drain: prologue stages + wreg complete

    for (int st = 1; st <= 78; ++st){
      const int thr  = (st <= 49) ? (50 - st) : -1;
      const int tsel = (st <= 49) ? st : 49;

      f32x4 acc[4][2];
      #pragma unroll
      for (int g = 0; g < 4; ++g)
        #pragma unroll
        for (int t = 0; t < 2; ++t) acc[g][t] = (f32x4){0.f,0.f,0.f,0.f};

      // ---- register half: k in [0,128), overlaps in-flight DMA ----
      #pragma unroll
      for (int ks = 0; ks < 4; ++ks){
        const bf16x8 afr = *(const bf16x8*)(Hl + llo*HLROW + ks*32 + lhi*8);
        #pragma unroll
        for (int g = 0; g < 4; ++g)
          #pragma unroll
          for (int t = 0; t < 2; ++t)
            acc[g][t] = __builtin_amdgcn_mfma_f32_16x16x32_bf16(afr, wreg[g][t][ks], acc[g][t], 0,0,0);
      }

      // ---- streamed half: logical chunks 4..7, buffers i&1 ----
      #pragma unroll
      for (int i = 0; i < 4; ++i){
        const bf16x8 afs = *(const bf16x8*)(Hl + llo*HLROW + (4+i)*32 + lhi*8);
        asm volatile("s_waitcnt vmcnt(8)" ::: "memory");
        __builtin_amdgcn_sched_barrier(0);
        __builtin_amdgcn_s_barrier();          // buf (i&1) fully staged
        __builtin_amdgcn_sched_barrier(0);
        const short* bb = wbuf + (i & 1)*32768;
        #pragma unroll
        for (int g = 0; g < 4; ++g)
          #pragma unroll
          for (int t = 0; t < 2; ++t){
            const int r  = ((g & 1) << 8) + (wv << 5) + t*16 + llo;
            const int ls = ((g >> 1) << 2) + lhi;
            const int p  = ls ^ (r & 7);
            const bf16x8 bfv = *(const bf16x8*)(bb + r*64 + p*8);
            acc[g][t] = __builtin_amdgcn_mfma_f32_16x16x32_bf16(afs, bfv, acc[g][t], 0,0,0);
          }
        asm volatile("s_waitcnt lgkmcnt(0)" ::: "memory");
        __builtin_amdgcn_sched_barrier(0);
        __builtin_amdgcn_s_barrier();          // all waves done reading buf
        __builtin_amdgcn_sched_barrier(0);
        // restage: logical chunk 4+((i+2)&3) into buf (i&1)
        {
          const int nc = (i + 2) & 3;
          const char* gsrc = (const char*)(ws + WS_WZ) + nc*65536 + wv*8192 + lane*16;
          char* ldst = smem_raw + (i & 1)*65536 + wv*8192;
          #pragma unroll
          for (int q = 0; q < 8; ++q) gld16(gsrc + q*1024, ldst + q*1024);
        }
      }

      // ---- gates + masked update (registers) ----
      #pragma unroll
      for (int r = 0; r < 4; ++r){
        const float r0 = relS[(lhi*4 + r)*100 + 2*tsel];
        const float r1 = relS[(lhi*4 + r)*100 + 2*tsel + 1];
        const bool mk = nh4[r] > thr;
        #pragma unroll
        for (int t = 0; t < 2; ++t){
          const float gi = acc[0][t][r] + r0*wf0[0][t] + r1*wf1[0][t] + wb[0][t];
          const float gf = acc[1][t][r] + r0*wf0[1][t] + r1*wf1[1][t] + wb[1][t];
          const float gg = acc[2][t][r] + r0*wf0[2][t] + r1*wf1[2][t] + wb[2][t];
          const float go = acc[3][t][r] + r0*wf0[3][t] + r1*wf1[3][t] + wb[3][t];
          const float c2 = sigf(gf)*C[r][t] + sigf(gi)*tanhfast(gg);
          const float h2 = sigf(go)*tanhfast(c2);
          if (mk){ C[r][t] = c2; ho[r][t] = h2; }
        }
      }
      // H-write (all Hl reads of this step finished at last chunk barrier)
      #pragma unroll
      for (int r = 0; r < 4; ++r)
        #pragma unroll
        for (int t = 0; t < 2; ++t)
          ((__hip_bfloat16*)Hl)[(lhi*4 + r)*HLROW + (wv<<5) + t*16 + llo] =
              __float2bfloat16(ho[r][t]);
      asm volatile("s_waitcnt lgkmcnt(0)" ::: "memory");
      __builtin_amdgcn_sched_barrier(0);
      __builtin_amdgcn_s_barrier();            // H update visible block-wide
      __builtin_amdgcn_sched_barrier(0);

      if (st >= 49){
        const int s = st - 49;
        const int a = wv*2 + (lane >> 5);
        const int sub = lane & 31;
        float z0 = 0.f, z1 = 0.f;
        const short* hp = Hl + a*HLROW + sub*8;
        #pragma unroll
        for (int i = 0; i < 8; ++i){
          const float h = bfs(hp[i]);
          z0 += h*vS[2*(sub*8 + i)];
          z1 += h*vS[2*(sub*8 + i) + 1];
        }
        #pragma unroll
        for (int o = 16; o > 0; o >>= 1){
          z0 += __shfl_down(z0, o, 32);
          z1 += __shfl_down(z1, o, 32);
        }
        if (sub == 0){
          ws[WS_Z + (s*NAG + n0 + a)*2]     = z0;
          ws[WS_Z + (s*NAG + n0 + a)*2 + 1] = z1;
        }
      }
    }
  }
  else if (b == 128){
    float* hT = (float*)smem_raw;
    float* cT = hT + 128;
    float* gT = cT + 128;
    if (tid < 128){ hT[tid] = th0[tid]; cT[tid] = tc0[tid]; }
    __syncthreads();
    const int ths = thsp[0];
    for (int t = 1; t < 50; ++t){
      const float x0 = trel[2*t], x1 = trel[2*t+1];
      float acc = x0*ws[WS_WFT + tid] + x1*ws[WS_WFT + 512 + tid] + ws[WS_BFT + tid];
      for (int k = 0; k < 128; ++k) acc += hT[k]*Whht[k*512 + tid];
      gT[tid] = acc;
      __syncthreads();
      if (tid < 128 && ths > 50 - t){
        const float ig = sigf(gT[tid]),          fg = sigf(gT[128 + tid]);
        const float gg = tanhfast(gT[256 + tid]), og = sigf(gT[384 + tid]);
        const float c2 = fg*cT[tid] + ig*gg;
        cT[tid] = c2; hT[tid] = og*tanhfast(c2);
      }
      __syncthreads();
    }
    if (tid < 128){ ws[WS_TH + tid] = hT[tid]; ws[WS_TC + tid] = cT[tid]; }
  }
  else {
    float* at  = (float*)smem_raw;
    float* red = at + 64;
    float* uv  = red + 512;
    const int t = LH - 1;
    const float tr0 = trel[2*t], tr1 = trel[2*t+1];
    const float tp0 = tpos[2*t], tp1 = tpos[2*t+1];
    if (tid < ADIM) at[tid] = tr0*Wtatt[tid] + tr1*Wtatt[ADIM+tid] + btatt[tid];
    int cnt = 0;
    #pragma unroll
    for (int i = 0; i < 4; ++i) cnt += (nhist[tid + 512*i] > (LH - t)) ? 1 : 0;
    red[tid] = (float)cnt;
    __syncthreads();
    if (tid == 0){
      float u0=0.f,u1=0.f,v=0.f;
      for (int k=0;k<ADIM;k++){ u0 += Wnatt[k]*at[k]; u1 += Wnatt[ADIM+k]*at[k]; v += bnatt[k]*at[k]; }
      uv[0]=u0; uv[1]=u1; uv[2]=v;
    }
    for (int s = 256; s > 0; s >>= 1){ if (tid < s) red[tid] += red[tid+s]; __syncthreads(); }
    const float currN = red[0];
    __syncthreads();
    const float u0 = uv[0], u1 = uv[1], v = uv[2];
    const float scale = currN * 0.125f;
    float sc[4]; float smax = -3.0e38f;
    #pragma unroll
    for (int i = 0; i < 4; ++i){
      const int n = tid + 512*i;
      const float p0 = npos[n*100 + 2*t], p1 = npos[n*100 + 2*t + 1];
      float s = scale * ((tp0-p0)*u0 + (tp1-p1)*u1 + v);
      s = (nhist[n] > (LH - t)) ? s : -1.0e30f;
      sc[i] = s; smax = fmaxf(smax, s);
    }
    red[tid] = smax; __syncthreads();
    for (int s = 256; s > 0; s >>= 1){ if (tid<s) red[tid] = fmaxf(red[tid], red[tid+s]); __syncthreads(); }
    smax = red[0]; __syncthreads();
    float ssum = 0.f;
    #pragma unroll
    for (int i = 0; i < 4; ++i){ sc[i] = __expf(sc[i]-smax); ssum += sc[i]; }
    red[tid] = ssum; __syncthreads();
    for (int s = 256; s > 0; s >>= 1){ if (tid<s) red[tid] += red[tid+s]; __syncthreads(); }
    const float inv = 1.0f / red[0];
    #pragma unroll
    for (int i = 0; i < 4; ++i) ws[WS_W49 + tid + 512*i] = sc[i]*inv;
    if (tid == 0) ws[WS_CN] = currN;
  }
}

// ---- Phase B: all 30 pred steps in one block ---------------------------------
template<int K>
__device__ __forceinline__ void bredN(const float* v, volatile float* scratch,
                                      volatile float* outv, int tid){
  const int lane = tid & 63, wv = tid >> 6;
  #pragma unroll
  for (int k = 0; k < K; ++k){
    float x = v[k];
    #pragma unroll
    for (int o = 32; o > 0; o >>= 1) x += __shfl_down(x, o, 64);
    if (lane == 0) scratch[k*8 + wv] = x;
  }
  __syncthreads();
  if (tid == 0){
    #pragma unroll
    for (int k = 0; k < K; ++k){
      float s = 0.f;
      for (int i = 0; i < 8; ++i) s += scratch[k*8 + i];
      outv[k] = s;
    }
  }
  __syncthreads();
}

__device__ __forceinline__ float bredMax1(float x, volatile float* scratch,
                                          volatile float* outv, int tid){
  const int lane = tid & 63, wv = tid >> 6;
  #pragma unroll
  for (int o = 32; o > 0; o >>= 1) x = fmaxf(x, __shfl_down(x, o, 64));
  if (lane == 0) scratch[wv] = x;
  __syncthreads();
  if (tid == 0){
    float s = -3.0e38f;
    for (int i = 0; i < 8; ++i) s = fmaxf(s, scratch[i]);
    outv[0] = s;
  }
  __syncthreads();
  return outv[0];
}

__global__ __launch_bounds__(512, 1) void k_phaseB(
    const float* __restrict__ img, const float* __restrict__ tpos,
    const float* __restrict__ npos, const float* __restrict__ nh0,
    const float* __restrict__ Wpred, const float* __restrict__ bpred,
    const float* __restrict__ Wtatt, const float* __restrict__ btatt,
    const float* __restrict__ Wnatt, const float* __restrict__ bnatt,
    float* __restrict__ ws, float* __restrict__ out)
{
  __shared__ float p0s[NAG], p1s[NAG];
  __shared__ float th[128], tc[128], gl[512], at[64];
  __shared__ float scratch[24];
  __shared__ float bc[8];
  const int tid = threadIdx.x, lane = tid & 63, wv = tid >> 6;

  bf16x8 wreg[16];
  {
    const short* wp = (const short*)(ws + WS_WHT) + tid*128;
    #pragma unroll
    for (int f = 0; f < 16; ++f) wreg[f] = *(const bf16x8*)(wp + f*8);
  }
  for (int n = tid; n < NAG; n += 512){
    p0s[n] = npos[n*100 + 98];
    p1s[n] = npos[n*100 + 99];
  }
  if (tid < 128){ th[tid] = ws[WS_TH + tid]; tc[tid] = ws[WS_TC + tid]; }

  {
    float v[2] = {0.f, 0.f};
    for (int k = tid; k < CNND; k += 512){
      v[0] += img[k]*Wpred[2*(128 + k)];
      v[1] += img[k]*Wpred[2*(128 + k) + 1];
    }
    bredN<2>(v, scratch, bc, tid);
  }
  const float imgW0 = bc[0], imgW1 = bc[1];
  {
    float v[2] = {0.f, 0.f};
    if (tid < 256){
      v[0] = nh0[tid]*Wpred[2*(128 + CNND + tid)];
      v[1] = nh0[tid]*Wpred[2*(128 + CNND + tid) + 1];
    }
    bredN<2>(v, scratch, bc + 2, tid);
  }
  const float fb0 = bc[2], fb1 = bc[3];
  const float currN = ws[WS_CN];
  float pos0 = tpos[98], pos1 = tpos[99];
  float u0 = 0.f, u1 = 0.f, A = 0.f;
  __syncthreads();

  for (int s = 0; s < PP; ++s){
    const float* zs = ws + WS_Z + s*(NAG*2);
    float hv0, hv1;
    if (s == 0){
      if (currN >= 1.0f){
        float v[2] = {0.f, 0.f};
        for (int n = tid; n < NAG; n += 512){
          const float w = ws[WS_W49 + n];
          v[0] += w*zs[2*n]; v[1] += w*zs[2*n + 1];
        }
        bredN<2>(v, scratch, bc, tid);
        hv0 = bc[0]; hv1 = bc[1];
      } else { hv0 = fb0; hv1 = fb1; }
    } else {
      float sc[4], mx = -3.0e38f;
      #pragma unroll
      for (int i = 0; i < 4; ++i){
        const int n = tid + 512*i;
        sc[i] = 256.0f * (A - (p0s[n]*u0 + p1s[n]*u1));
        mx = fmaxf(mx, sc[i]);
      }
      mx = bredMax1(mx, scratch, bc + 7, tid);
      float v[3] = {0.f, 0.f, 0.f};
      #pragma unroll
      for (int i = 0; i < 4; ++i){
        const int n = tid + 512*i;
        const float e = __expf(sc[i] - mx);
        v[0] += e; v[1] += e*zs[2*n]; v[2] += e*zs[2*n + 1];
      }
      bredN<3>(v, scratch, bc, tid);
      const float inv = 1.0f / bc[0];
      hv0 = bc[1]*inv; hv1 = bc[2]*inv;
    }
    {
      float v[2] = {0.f, 0.f};
      if (tid < 128){
        v[0] = th[tid]*Wpred[2*tid];
        v[1] = th[tid]*Wpred[2*tid + 1];
      }
      bredN<2>(v, scratch, bc + 2, tid);
    }
    const float pr0 = bc[2] + imgW0 + hv0 + bpred[0];
    const float pr1 = bc[3] + imgW1 + hv1 + bpred[1];
    if (tid == 0){ out[2*s] = pr0; out[2*s + 1] = pr1; }
    pos0 += pr0; pos1 += pr1;

    {
      float g = pr0*ws[WS_WFT + tid] + pr1*ws[WS_WFT + 512 + tid] + ws[WS_BFT + tid];
      #pragma unroll
      for (int f = 0; f < 16; ++f){
        #pragma unroll
        for (int i = 0; i < 8; ++i)
          g += bfs(wreg[f][i]) * th[f*8 + i];
      }
      gl[tid] = g;
    }
    __syncthreads();
    float hnew = 0.f, cnew = 0.f;
    if (tid < 128){
      const float ig = sigf(gl[tid]),           fg = sigf(gl[128 + tid]);
      const float gg = tanhfast(gl[256 + tid]), og = sigf(gl[384 + tid]);
      cnew = fg*tc[tid] + ig*gg;
      hnew = og*tanhfast(cnew);
    }
    __syncthreads();
    if (tid < 128){ th[tid] = hnew; tc[tid] = cnew; }

    if (tid < ADIM) at[tid] = pr0*Wtatt[tid] + pr1*Wtatt[ADIM + tid] + btatt[tid];
    __syncthreads();
    if (wv == 0){
      float uu0 = Wnatt[lane]*at[lane];
      float uu1 = Wnatt[ADIM + lane]*at[lane];
      float vv  = bnatt[lane]*at[lane];
      #pragma unroll
      for (int o = 32; o > 0; o >>= 1){
        uu0 += __shfl_down(uu0, o, 64);
        uu1 += __shfl_down(uu1, o, 64);
        vv  += __shfl_down(vv,  o, 64);
      }
      if (lane == 0){
        bc[4] = uu0; bc[5] = uu1;
        bc[6] = pos0*uu0 + pos1*uu1 + vv;
      }
    }
    __syncthreads();
    u0 = bc[4]; u1 = bc[5]; A = bc[6];
  }
}

extern "C" void kernel_launch(void* const* d_in, const int* in_sizes, int n_in,
                              void* d_out, int out_size, void* d_ws, size_t ws_size,
                              hipStream_t stream) {
  const float* img   = (const float*)d_in[0];
  const float* tpos  = (const float*)d_in[1];
  const float* trel  = (const float*)d_in[2];
  const float* npos  = (const float*)d_in[3];
  const float* nrel  = (const float*)d_in[4];
  const int*   nhist = (const int*)d_in[5];
  const int*   ths   = (const int*)d_in[6];
  const float* th0   = (const float*)d_in[7];
  const float* tc0   = (const float*)d_in[8];
  const float* Wtemb = (const float*)d_in[9];
  const float* btemb = (const float*)d_in[10];
  const float* Wiht  = (const float*)d_in[11];
  const float* Whht  = (const float*)d_in[12];
  const float* biht  = (const float*)d_in[13];
  const float* bhht  = (const float*)d_in[14];
  const float* Wtatt = (const float*)d_in[15];
  const float* btatt = (const float*)d_in[16];
  const float* nh0   = (const float*)d_in[17];
  const float* nc0   = (const float*)d_in[18];
  const float* Wnemb = (const float*)d_in[19];
  const float* bnemb = (const float*)d_in[20];
  const float* Wihn  = (const float*)d_in[21];
  const float* Whhn  = (const float*)d_in[22];
  const float* bihn  = (const float*)d_in[23];
  const float* bhhn  = (const float*)d_in[24];
  const float* Wnatt = (const float*)d_in[25];
  const float* bnatt = (const float*)d_in[26];
  const float* Wpred = (const float*)d_in[27];
  const float* bpred = (const float*)d_in[28];
  float* ws  = (float*)d_ws;
  float* out = (float*)d_out;

  const int ldsA = 131072 + 16*HLROW*2 + 1600*4 + 512*4;   // 147008 B

  k_prep<<<193, 256, 0, stream>>>(Whhn, Whht, Wnemb, bnemb, Wihn, bihn, bhhn,
                                  Wtemb, btemb, Wiht, biht, bhht, ws);
  k_phaseA<<<130, 512, ldsA, stream>>>(nh0, nc0, nrel, nhist, Wpred,
                                       trel, ths, Whht, th0, tc0,
                                       tpos, npos, Wtatt, btatt, Wnatt, bnatt, ws);
  k_phaseB<<<1, 512, 0, stream>>>(img, tpos, npos, nh0, Wpred, bpred,
                                  Wtatt, btatt, Wnatt, bnatt, ws, out);
}